// Round 4
// baseline (625.927 us; speedup 1.0000x reference)
//
#include <hip/hip_runtime.h>
#include <math.h>

#define N_NODES 50000
#define N_EDGES 800000
#define DIM 128
#define PAD 120                 // bucket capacity; Poisson(16) P(>=120) ~ 0

// R16 binned scatter: 64-node bins, one block per bin in phase B
#define BIN_SHIFT 6
#define BIN_NODES 64
#define N_BINS 782              // ceil(50000/64)
#define BIN_CAP 1536            // E[fill]=1024, sigma=32 -> +16 sigma

typedef __attribute__((ext_vector_type(8))) short short8;
typedef __attribute__((ext_vector_type(4))) float floatx4;

// f32 -> bf16 bits, round-to-nearest-even (matches v_cvt / numpy)
__device__ __forceinline__ unsigned short f32_to_bf16(float f) {
    unsigned int u = __float_as_uint(f);
    u += 0x7fffu + ((u >> 16) & 1u);
    return (unsigned short)(u >> 16);
}
__device__ __forceinline__ float bf16_to_f32(unsigned short h) {
    return __uint_as_float((unsigned int)h << 16);
}

// ---------------- prep: zero bin counters + build all 9 folded bf16 W ------
// Fold cg*W + cm*I ONCE (betas are compile-time constants of the layer idx).
// WTg layout: matrix m at m*16384, element [n][k] = W'[k][n] (transposed).
__global__ __launch_bounds__(256) void prep(const float* __restrict__ Wlin,
                                            const float* __restrict__ Wcv,
                                            int* __restrict__ bc,
                                            unsigned short* __restrict__ WTg) {
    int i = blockIdx.x * 256 + threadIdx.x;   // grid 576*256 = 147456 = 9*16384
    if (i < N_BINS) bc[i] = 0;
    int m = i >> 14;          // matrix 0..8
    int n = (i >> 7) & 127;   // output col (= row of WT)
    int k = i & 127;          // input dim
    float v;
    if (m == 0) {
        v = Wlin[k * 128 + n];
    } else {
        int l = m - 1;
        float beta = logf(0.5f / (float)(l + 1) + 1.0f);
        v = beta * Wcv[(size_t)l * 16384 + k * 128 + n]
            + ((n == k) ? (1.0f - beta) : 0.0f);
    }
    WTg[i] = f32_to_bf16(v);
}

// ---------------- phase A: bin edges (append, contiguous per bin) ----------
// R16: scatter_pad's 50MB WRITE_SIZE was ~6x line-writeback amplification
// (same-dst 8B writes temporally scattered -> dirty lines evicted between
// appends). Bin appends keep only 782 open tail-lines dirty (~50KB) ->
// writeback ~= touched bytes. src<50000 fits 16 bits; pack dloc in 16..21.
__global__ __launch_bounds__(256) void bin_edges(const int* __restrict__ src,
                                                 const int* __restrict__ dst,
                                                 const float* __restrict__ ew,
                                                 int* __restrict__ bc,
                                                 int2* __restrict__ binbuf) {
    int e = blockIdx.x * 256 + threadIdx.x;
    if (e < N_EDGES) {
        int d = dst[e];
        int bin = d >> BIN_SHIFT;
        int pos = atomicAdd(&bc[bin], 1);
        if (pos < BIN_CAP) {                   // +16 sigma guard, unreachable
            int2 p;
            p.x = src[e] | ((d & (BIN_NODES - 1)) << 16);
            p.y = __float_as_int(ew[e]);
            binbuf[(size_t)bin * BIN_CAP + pos] = p;
        }
    }
}

// ---------------- phase B: bin -> padded buckets (localized writes) --------
// One block per bin: coalesced bin reads, LDS-atomic per-node counting (bin
// owns its 64-node range exclusively -> cnt written once, no global RMW),
// bucket writes confined to a 60KB range -> each line written back once.
__global__ __launch_bounds__(256) void bin_scatter(const int* __restrict__ bc,
                                                   const int2* __restrict__ binbuf,
                                                   int* __restrict__ cnt,
                                                   int2* __restrict__ bucket) {
    __shared__ int c[BIN_NODES];
    int b = blockIdx.x;
    int tid = threadIdx.x;
    if (tid < BIN_NODES) c[tid] = 0;
    __syncthreads();
    int n = min(bc[b], BIN_CAP);
    int base = b << BIN_SHIFT;
    for (int i = tid; i < n; i += 256) {
        int2 p = binbuf[(size_t)b * BIN_CAP + i];
        int dloc = (p.x >> 16) & (BIN_NODES - 1);
        int pos = atomicAdd(&c[dloc], 1);
        if (pos < PAD) {                       // structurally unreachable
            int2 q; q.x = p.x & 0xFFFF; q.y = p.y;
            bucket[(size_t)(base + dloc) * PAD + pos] = q;
        }
    }
    __syncthreads();
    if (tid < BIN_NODES && base + tid < N_NODES)
        cnt[base + tid] = min(c[tid], PAD);
}

// ---------------- x0 = relu(x @ W_lin + b) -> bf16 rows --------------------
// B from prefolded bf16 WTg, staged through LDS (R14 proved in-loop global
// B-frag reads sit on the MFMA critical path; LDS ds_read_b128 ~12cy wins).
__global__ __launch_bounds__(256) void gemm_x0(const float* __restrict__ x,
                                               const unsigned short* __restrict__ WTg,
                                               const float* __restrict__ bias,
                                               unsigned short* __restrict__ x0B) {
    __shared__ unsigned short WT[128][136];   // +8 pad: 2-way max on b128 reads
    for (int idx = threadIdx.x; idx < 2048; idx += 256) {
        int n = idx >> 4, c = idx & 15;
        *(short8*)(void*)&WT[n][c * 8] =
            *(const short8*)(const void*)(WTg + n * 128 + c * 8);
    }
    __syncthreads();
    int wave = threadIdx.x >> 6;
    int lane = threadIdx.x & 63;
    int r0 = (blockIdx.x * 4 + wave) * 16;
    if (r0 >= N_NODES) return;                 // 16 | 50000, full tiles only
    int mrow = lane & 15;
    int quad = lane >> 4;
    floatx4 acc[8];
#pragma unroll
    for (int t = 0; t < 8; t++) acc[t] = {0.f, 0.f, 0.f, 0.f};
#pragma unroll
    for (int k0 = 0; k0 < 128; k0 += 32) {
        const float* arow = x + (size_t)(r0 + mrow) * DIM;
        floatx4 alo = *(const floatx4*)(const void*)(arow + k0 + quad * 8);
        floatx4 ahi = *(const floatx4*)(const void*)(arow + k0 + quad * 8 + 4);
        short8 a;
#pragma unroll
        for (int j = 0; j < 4; j++) a[j] = (short)f32_to_bf16(alo[j]);
#pragma unroll
        for (int j = 0; j < 4; j++) a[4 + j] = (short)f32_to_bf16(ahi[j]);
#pragma unroll
        for (int t = 0; t < 8; t++) {
            short8 b = *(const short8*)(const void*)(&WT[t * 16 + mrow][k0 + quad * 8]);
            acc[t] = __builtin_amdgcn_mfma_f32_16x16x32_bf16(a, b, acc[t], 0, 0, 0);
        }
    }
    // C/D layout: col = lane&15, row = quad*4 + i  [verified m89/m91]
#pragma unroll
    for (int t = 0; t < 8; t++) {
        int col = t * 16 + mrow;
        float bv = bias[col];
#pragma unroll
        for (int i = 0; i < 4; i++) {
            int row = r0 + quad * 4 + i;
            float v = fmaxf(acc[t][i] + bv, 0.f);
            x0B[(size_t)row * DIM + col] = f32_to_bf16(v);
        }
    }
}

// ---------------- fused SpMM + residual mix + GEMM (one dispatch/layer) ----
// R3-verified: runs at the 46us gather floor WITH the MFMA tail riding free
// (absent from top-5 at 47.08 cut). 8 waves x 4 nodes gather (eg/ILP-4), mix
// with x0, park bf16 m rows in M-LDS, MFMA tail against LDS-staged W'T.
// launch_bounds (512,4) exactly — (512,6) coincided with +7us/layer in R14.
__global__ __launch_bounds__(512, 4) void layer_fused(
        const unsigned short* __restrict__ hB,
        const unsigned short* __restrict__ x0B,
        const int* __restrict__ cnt,
        const int2* __restrict__ bucket,
        const unsigned short* __restrict__ WTg,
        float* __restrict__ outF,
        unsigned short* __restrict__ outB) {
    __shared__ unsigned short WT[128][136];   // W'T bf16, +8 pad
    __shared__ unsigned short M[32][136];     // mixed m rows, bf16
    int tid = threadIdx.x;
    for (int idx = tid; idx < 2048; idx += 512) {
        int n = idx >> 4, c = idx & 15;
        *(short8*)(void*)&WT[n][c * 8] =
            *(const short8*)(const void*)(WTg + n * 128 + c * 8);
    }
    int wave = tid >> 6;
    int lane = tid & 63;
    int eg = lane >> 4;               // edge group 0..3
    int fb = (lane & 15) * 8;         // feature octet
    int r0 = blockIdx.x * 32;

    for (int s = 0; s < 4; s++) {
        int row = (wave << 2) + s;    // 0..31, unique per (wave,s)
        int node = r0 + row;
        float acc[8] = {0.f, 0.f, 0.f, 0.f, 0.f, 0.f, 0.f, 0.f};
        if (node < N_NODES) {
            int end = min(cnt[node], PAD);
            if (end > 0) {
                const int2* ep = bucket + (size_t)node * PAD;
                int last = end - 1;
                for (int i = 0; i < end; i += 16) {
                    int i0 = i + eg, i1 = i0 + 4, i2 = i0 + 8, i3 = i0 + 12;
                    int2 e0 = ep[min(i0, last)];
                    int2 e1 = ep[min(i1, last)];
                    int2 e2 = ep[min(i2, last)];
                    int2 e3 = ep[min(i3, last)];
                    short8 r0v = *(const short8*)(const void*)(hB + (size_t)e0.x * DIM + fb);
                    short8 r1v = *(const short8*)(const void*)(hB + (size_t)e1.x * DIM + fb);
                    short8 r2v = *(const short8*)(const void*)(hB + (size_t)e2.x * DIM + fb);
                    short8 r3v = *(const short8*)(const void*)(hB + (size_t)e3.x * DIM + fb);
                    float w0 = (i0 < end) ? __int_as_float(e0.y) : 0.f;
                    float w1 = (i1 < end) ? __int_as_float(e1.y) : 0.f;
                    float w2 = (i2 < end) ? __int_as_float(e2.y) : 0.f;
                    float w3 = (i3 < end) ? __int_as_float(e3.y) : 0.f;
#pragma unroll
                    for (int j = 0; j < 8; j++) {
                        acc[j] = fmaf(w0, bf16_to_f32((unsigned short)r0v[j]), acc[j]);
                        acc[j] = fmaf(w1, bf16_to_f32((unsigned short)r1v[j]), acc[j]);
                        acc[j] = fmaf(w2, bf16_to_f32((unsigned short)r2v[j]), acc[j]);
                        acc[j] = fmaf(w3, bf16_to_f32((unsigned short)r3v[j]), acc[j]);
                    }
                }
            }
        }
        // reduce the 4 edge groups into lanes 0..15
#pragma unroll
        for (int j = 0; j < 8; j++) {
            acc[j] += __shfl_down(acc[j], 32);
            acc[j] += __shfl_down(acc[j], 16);
        }
        if (lane < 16) {
            short8 o;
            if (node < N_NODES) {
                short8 xv = *(const short8*)(const void*)(x0B + (size_t)node * DIM + fb);
#pragma unroll
                for (int j = 0; j < 8; j++)
                    o[j] = (short)f32_to_bf16(0.9f * acc[j]
                                              + 0.1f * bf16_to_f32((unsigned short)xv[j]));
            } else {
#pragma unroll
                for (int j = 0; j < 8; j++) o[j] = 0;
            }
            *(short8*)(void*)&M[row][fb] = o;
        }
    }
    __syncthreads();

    // ---- GEMM tail: out = relu(M @ W') ; 8 waves cover 2x8 16x16 tiles ----
    int mrow = lane & 15;
    int quad = lane >> 4;
    int rt = wave >> 2;               // row tile 0..1
    int ctb = (wave & 3) * 2;         // col tile base 0,2,4,6
    floatx4 acc2[2];
    acc2[0] = {0.f, 0.f, 0.f, 0.f};
    acc2[1] = {0.f, 0.f, 0.f, 0.f};
#pragma unroll
    for (int k0 = 0; k0 < 128; k0 += 32) {
        short8 a = *(const short8*)(const void*)(&M[rt * 16 + mrow][k0 + quad * 8]);
#pragma unroll
        for (int t = 0; t < 2; t++) {
            short8 b = *(const short8*)(const void*)(&WT[(ctb + t) * 16 + mrow][k0 + quad * 8]);
            acc2[t] = __builtin_amdgcn_mfma_f32_16x16x32_bf16(a, b, acc2[t], 0, 0, 0);
        }
    }
#pragma unroll
    for (int t = 0; t < 2; t++) {
        int col = (ctb + t) * 16 + mrow;
#pragma unroll
        for (int i = 0; i < 4; i++) {
            int row = r0 + rt * 16 + quad * 4 + i;
            if (row < N_NODES) {
                float v = fmaxf(acc2[t][i], 0.f);
                size_t off = (size_t)row * DIM + col;
                if (outF) outF[off] = v;
                if (outB) outB[off] = f32_to_bf16(v);
            }
        }
    }
}

// ---------------- launch ----------------

extern "C" void kernel_launch(void* const* d_in, const int* in_sizes, int n_in,
                              void* d_out, int out_size, void* d_ws, size_t ws_size,
                              hipStream_t stream) {
    const float* x    = (const float*)d_in[0];
    const float* ew   = (const float*)d_in[1];
    const float* Wlin = (const float*)d_in[2];
    const float* blin = (const float*)d_in[3];
    const float* Wcv  = (const float*)d_in[4];
    const int* eidx = (const int*)d_in[5];
    const int* esrc = eidx;
    const int* edst = eidx + N_EDGES;
    float* out = (float*)d_out;

    char* ws = (char*)d_ws;
    unsigned short* x0B = (unsigned short*)(ws);             // 12.8 MB bf16 x0
    unsigned short* hA  = (unsigned short*)(ws + 12800000);  // 12.8 MB bf16 h ping
    unsigned short* hB2 = (unsigned short*)(ws + 25600000);  // 12.8 MB bf16 h pong
    int* cnt            = (int*)(ws + 38400000);             // N*4 degree
    int2* bucket        = (int2*)(ws + 38600064);            // N*PAD*8 = 48.0 MB
    unsigned short* WTg = (unsigned short*)(ws + 86600064);  // 9*128*128*2 = 288 KB
    int* bc             = (int*)(ws + 86894976);             // N_BINS*4 bin cursors
    // binbuf overlaps hA (consumed by bin_scatter before layer 0 writes hA)
    int2* binbuf        = (int2*)hA;                         // 782*1536*8 = 9.6 MB
    // total ~86.9 MB

    // prep: bc zeroing + all 9 folded/transposed bf16 weight matrices
    prep<<<576, 256, 0, stream>>>(Wlin, Wcv, bc, WTg);

    // two-phase binned bucket build (R16: kills 6x line-writeback amp)
    bin_edges<<<(N_EDGES + 255) / 256, 256, 0, stream>>>(esrc, edst, ew, bc, binbuf);
    bin_scatter<<<N_BINS, 256, 0, stream>>>(bc, binbuf, cnt, bucket);

    // x0 gemm: standalone, B from prefolded WTg via LDS
    gemm_x0<<<(N_NODES + 63) / 64, 256, 0, stream>>>(x, WTg, blin, x0B);

    const unsigned short* hin = x0B;
    for (int l = 0; l < 8; l++) {
        unsigned short* hout = (l == 7) ? nullptr : ((l & 1) ? hB2 : hA);
        layer_fused<<<1563, 512, 0, stream>>>(hin, x0B, cnt, bucket,
                                              WTg + (size_t)(1 + l) * 16384,
                                              (l == 7) ? out : nullptr, hout);
        hin = hout;
    }
}

// Round 5
// 454.853 us; speedup vs baseline: 1.3761x; 1.3761x over previous
//
#include <hip/hip_runtime.h>
#include <math.h>

#define N_NODES 50000
#define N_EDGES 800000
#define DIM 128
#define PAD 120                 // bucket capacity; realized max degree ~45

// R17 sort-based bucket build (both R4 failure modes addressed):
//  - no global atomics (R4: 1024-deep same-address chains @188ns = 192us)
//  - full-line single-block writes (R4: every 8B cross-XCD write = 64B wb)
#define EPB 2048                // edges per phase-A block
#define NBLKA 391               // ceil(800000/2048)
#define BIN_SHIFT 8
#define NBIN 196                // ceil(50000/256); bin = dst>>8
#define HISTW 197               // per-block stored scan: base[0..196]

typedef __attribute__((ext_vector_type(8))) short short8;
typedef __attribute__((ext_vector_type(4))) float floatx4;

// f32 -> bf16 bits, round-to-nearest-even (matches v_cvt / numpy)
__device__ __forceinline__ unsigned short f32_to_bf16(float f) {
    unsigned int u = __float_as_uint(f);
    u += 0x7fffu + ((u >> 16) & 1u);
    return (unsigned short)(u >> 16);
}
__device__ __forceinline__ float bf16_to_f32(unsigned short h) {
    return __uint_as_float((unsigned int)h << 16);
}

// ---------------- prep: build all 9 folded/transposed bf16 W ---------------
// Fold cg*W + cm*I ONCE (betas are compile-time constants of the layer idx).
// WTg layout: matrix m at m*16384, element [n][k] = W'[k][n] (transposed).
__global__ __launch_bounds__(256) void prep(const float* __restrict__ Wlin,
                                            const float* __restrict__ Wcv,
                                            unsigned short* __restrict__ WTg) {
    int i = blockIdx.x * 256 + threadIdx.x;   // grid 576*256 = 147456 = 9*16384
    int m = i >> 14;          // matrix 0..8
    int n = (i >> 7) & 127;   // output col (= row of WT)
    int k = i & 127;          // input dim
    float v;
    if (m == 0) {
        v = Wlin[k * 128 + n];
    } else {
        int l = m - 1;
        float beta = logf(0.5f / (float)(l + 1) + 1.0f);
        v = beta * Wcv[(size_t)l * 16384 + k * 128 + n]
            + ((n == k) ? (1.0f - beta) : 0.0f);
    }
    WTg[i] = f32_to_bf16(v);
}

// ---------------- phase A: block-local LDS counting sort -------------------
// Each block sorts its 2048 edges by dst-bin in LDS, then dumps the sorted
// buffer CONTIGUOUSLY (16KB, full-line coalesced, single-block-owned lines
// -> writeback == payload). Per-block bin starts (exclusive scan, 197 ints)
// go to histg. No global atomics anywhere; exact, no capacity clamp.
__global__ __launch_bounds__(256) void bin_sort(const int* __restrict__ src,
                                                const int* __restrict__ dst,
                                                const float* __restrict__ ew,
                                                int* __restrict__ histg,
                                                int2* __restrict__ binbuf) {
    __shared__ int hist[NBIN];
    __shared__ int base[NBIN + 1];
    __shared__ int cur[NBIN];
    __shared__ int2 sorted[EPB];          // 16 KB
    int tid = threadIdx.x;
    int e0 = blockIdx.x * EPB;
    if (tid < NBIN) hist[tid] = 0;
    __syncthreads();
    // pass 1: histogram of dst bins (LDS atomics, ~10-deep chains)
    for (int i = tid; i < EPB; i += 256) {
        int e = e0 + i;
        if (e < N_EDGES) atomicAdd(&hist[dst[e] >> BIN_SHIFT], 1);
    }
    __syncthreads();
    // exclusive scan base[0..196] (Hillis-Steele over 197 entries)
    if (tid < NBIN) base[tid + 1] = hist[tid];
    if (tid == 0) base[0] = 0;
    __syncthreads();
    for (int off = 1; off < NBIN + 1; off <<= 1) {
        int v = 0;
        if (tid >= off && tid <= NBIN) v = base[tid - off];
        __syncthreads();
        if (tid >= off && tid <= NBIN) base[tid] += v;
        __syncthreads();
    }
    if (tid < NBIN) cur[tid] = base[tid];
    __syncthreads();
    // pass 2: scatter into LDS sorted order (dst re-read is L2-hot)
    for (int i = tid; i < EPB; i += 256) {
        int e = e0 + i;
        if (e < N_EDGES) {
            int d = dst[e];
            int pos = atomicAdd(&cur[d >> BIN_SHIFT], 1);
            int2 p;
            p.x = (src[e] & 0xFFFF) | (d << 16);   // src<65536, d<65536
            p.y = __float_as_int(ew[e]);
            sorted[pos] = p;
        }
    }
    __syncthreads();
    int total = base[NBIN];
    // contiguous dump: full-line coalesced writes, block-exclusive lines
    for (int k = tid; k < total; k += 256)
        binbuf[(size_t)blockIdx.x * EPB + k] = sorted[k];
    // store the block's bin starts (exclusive scan incl. total at [196])
    if (tid <= NBIN) histg[blockIdx.x * HISTW + tid] = base[tid];
}

// ---------------- phase B: bin-local distribute to padded buckets ----------
// One block per (bin=256 nodes, half=128 nodes). Streams the bin's edges
// from all 391 block-segments (prefix-scan + binary search, all LDS), ranks
// per node via LDS atomics, writes buckets confined to a 16KB node range
// from a SINGLE block -> same-node writes land in one L2 residency window
// -> write-combined (R4 lesson: this is the only way to avoid E*64B wb).
__global__ __launch_bounds__(512) void bin_scatter(const int* __restrict__ histg,
                                                   const int2* __restrict__ binbuf,
                                                   int* __restrict__ cnt,
                                                   int2* __restrict__ bucket) {
    __shared__ int segstart[NBLKA];       // global slot of bin's chunk in seg s
    __shared__ int pref[NBLKA + 1];       // exclusive scan of chunk sizes
    __shared__ int c[128];
    int bin = blockIdx.x >> 1;
    int half = blockIdx.x & 1;
    int tid = threadIdx.x;
    if (tid < 128) c[tid] = 0;
    if (tid < NBLKA) {
        int bs = histg[tid * HISTW + bin];
        int be = histg[tid * HISTW + bin + 1];
        segstart[tid] = tid * EPB + bs;
        pref[tid + 1] = be - bs;
    }
    if (tid == 0) pref[0] = 0;
    __syncthreads();
    for (int off = 1; off < NBLKA + 1; off <<= 1) {
        int v = 0;
        if (tid >= off && tid <= NBLKA) v = pref[tid - off];
        __syncthreads();
        if (tid >= off && tid <= NBLKA) pref[tid] += v;
        __syncthreads();
    }
    int T = pref[NBLKA];
    for (int idx = tid; idx < T; idx += 512) {
        // find segment: largest s with pref[s] <= idx (LDS binary search)
        int lo = 0, hi = NBLKA - 1;
        while (lo < hi) {
            int mid = (lo + hi + 1) >> 1;
            if (pref[mid] <= idx) lo = mid; else hi = mid - 1;
        }
        int2 p = binbuf[(size_t)segstart[lo] + (idx - pref[lo])];
        int d = ((unsigned)p.x) >> 16;
        int dloc = d & ((1 << BIN_SHIFT) - 1);
        if ((dloc >> 7) == half) {
            int pos = atomicAdd(&c[dloc & 127], 1);
            if (pos < PAD) {               // realized max degree ~45, safe
                int2 q; q.x = p.x & 0xFFFF; q.y = p.y;
                bucket[(size_t)d * PAD + pos] = q;
            }
        }
    }
    __syncthreads();
    int node0 = (bin << BIN_SHIFT) + (half << 7);
    if (tid < 128 && node0 + tid < N_NODES)
        cnt[node0 + tid] = min(c[tid], PAD);
}

// ---------------- x0 = relu(x @ W_lin + b) -> bf16 rows --------------------
// B from prefolded bf16 WTg, staged through LDS (R14 proved in-loop global
// B-frag reads sit on the MFMA critical path; LDS ds_read_b128 ~12cy wins).
__global__ __launch_bounds__(256) void gemm_x0(const float* __restrict__ x,
                                               const unsigned short* __restrict__ WTg,
                                               const float* __restrict__ bias,
                                               unsigned short* __restrict__ x0B) {
    __shared__ unsigned short WT[128][136];   // +8 pad: 2-way max on b128 reads
    for (int idx = threadIdx.x; idx < 2048; idx += 256) {
        int n = idx >> 4, c = idx & 15;
        *(short8*)(void*)&WT[n][c * 8] =
            *(const short8*)(const void*)(WTg + n * 128 + c * 8);
    }
    __syncthreads();
    int wave = threadIdx.x >> 6;
    int lane = threadIdx.x & 63;
    int r0 = (blockIdx.x * 4 + wave) * 16;
    if (r0 >= N_NODES) return;                 // 16 | 50000, full tiles only
    int mrow = lane & 15;
    int quad = lane >> 4;
    floatx4 acc[8];
#pragma unroll
    for (int t = 0; t < 8; t++) acc[t] = {0.f, 0.f, 0.f, 0.f};
#pragma unroll
    for (int k0 = 0; k0 < 128; k0 += 32) {
        const float* arow = x + (size_t)(r0 + mrow) * DIM;
        floatx4 alo = *(const floatx4*)(const void*)(arow + k0 + quad * 8);
        floatx4 ahi = *(const floatx4*)(const void*)(arow + k0 + quad * 8 + 4);
        short8 a;
#pragma unroll
        for (int j = 0; j < 4; j++) a[j] = (short)f32_to_bf16(alo[j]);
#pragma unroll
        for (int j = 0; j < 4; j++) a[4 + j] = (short)f32_to_bf16(ahi[j]);
#pragma unroll
        for (int t = 0; t < 8; t++) {
            short8 b = *(const short8*)(const void*)(&WT[t * 16 + mrow][k0 + quad * 8]);
            acc[t] = __builtin_amdgcn_mfma_f32_16x16x32_bf16(a, b, acc[t], 0, 0, 0);
        }
    }
    // C/D layout: col = lane&15, row = quad*4 + i  [verified m89/m91]
#pragma unroll
    for (int t = 0; t < 8; t++) {
        int col = t * 16 + mrow;
        float bv = bias[col];
#pragma unroll
        for (int i = 0; i < 4; i++) {
            int row = r0 + quad * 4 + i;
            float v = fmaxf(acc[t][i] + bv, 0.f);
            x0B[(size_t)row * DIM + col] = f32_to_bf16(v);
        }
    }
}

// ---------------- fused SpMM + residual mix + GEMM (one dispatch/layer) ----
// R3-verified: runs at the 46us gather floor WITH the MFMA tail riding free
// (absent from top-5 at 47.08 cut). 8 waves x 4 nodes gather (eg/ILP-4), mix
// with x0, park bf16 m rows in M-LDS, MFMA tail against LDS-staged W'T.
// launch_bounds (512,4) exactly — (512,6) coincided with +7us/layer in R14.
__global__ __launch_bounds__(512, 4) void layer_fused(
        const unsigned short* __restrict__ hB,
        const unsigned short* __restrict__ x0B,
        const int* __restrict__ cnt,
        const int2* __restrict__ bucket,
        const unsigned short* __restrict__ WTg,
        float* __restrict__ outF,
        unsigned short* __restrict__ outB) {
    __shared__ unsigned short WT[128][136];   // W'T bf16, +8 pad
    __shared__ unsigned short M[32][136];     // mixed m rows, bf16
    int tid = threadIdx.x;
    for (int idx = tid; idx < 2048; idx += 512) {
        int n = idx >> 4, c = idx & 15;
        *(short8*)(void*)&WT[n][c * 8] =
            *(const short8*)(const void*)(WTg + n * 128 + c * 8);
    }
    int wave = tid >> 6;
    int lane = tid & 63;
    int eg = lane >> 4;               // edge group 0..3
    int fb = (lane & 15) * 8;         // feature octet
    int r0 = blockIdx.x * 32;

    for (int s = 0; s < 4; s++) {
        int row = (wave << 2) + s;    // 0..31, unique per (wave,s)
        int node = r0 + row;
        float acc[8] = {0.f, 0.f, 0.f, 0.f, 0.f, 0.f, 0.f, 0.f};
        if (node < N_NODES) {
            int end = min(cnt[node], PAD);
            if (end > 0) {
                const int2* ep = bucket + (size_t)node * PAD;
                int last = end - 1;
                for (int i = 0; i < end; i += 16) {
                    int i0 = i + eg, i1 = i0 + 4, i2 = i0 + 8, i3 = i0 + 12;
                    int2 e0 = ep[min(i0, last)];
                    int2 e1 = ep[min(i1, last)];
                    int2 e2 = ep[min(i2, last)];
                    int2 e3 = ep[min(i3, last)];
                    short8 r0v = *(const short8*)(const void*)(hB + (size_t)e0.x * DIM + fb);
                    short8 r1v = *(const short8*)(const void*)(hB + (size_t)e1.x * DIM + fb);
                    short8 r2v = *(const short8*)(const void*)(hB + (size_t)e2.x * DIM + fb);
                    short8 r3v = *(const short8*)(const void*)(hB + (size_t)e3.x * DIM + fb);
                    float w0 = (i0 < end) ? __int_as_float(e0.y) : 0.f;
                    float w1 = (i1 < end) ? __int_as_float(e1.y) : 0.f;
                    float w2 = (i2 < end) ? __int_as_float(e2.y) : 0.f;
                    float w3 = (i3 < end) ? __int_as_float(e3.y) : 0.f;
#pragma unroll
                    for (int j = 0; j < 8; j++) {
                        acc[j] = fmaf(w0, bf16_to_f32((unsigned short)r0v[j]), acc[j]);
                        acc[j] = fmaf(w1, bf16_to_f32((unsigned short)r1v[j]), acc[j]);
                        acc[j] = fmaf(w2, bf16_to_f32((unsigned short)r2v[j]), acc[j]);
                        acc[j] = fmaf(w3, bf16_to_f32((unsigned short)r3v[j]), acc[j]);
                    }
                }
            }
        }
        // reduce the 4 edge groups into lanes 0..15
#pragma unroll
        for (int j = 0; j < 8; j++) {
            acc[j] += __shfl_down(acc[j], 32);
            acc[j] += __shfl_down(acc[j], 16);
        }
        if (lane < 16) {
            short8 o;
            if (node < N_NODES) {
                short8 xv = *(const short8*)(const void*)(x0B + (size_t)node * DIM + fb);
#pragma unroll
                for (int j = 0; j < 8; j++)
                    o[j] = (short)f32_to_bf16(0.9f * acc[j]
                                              + 0.1f * bf16_to_f32((unsigned short)xv[j]));
            } else {
#pragma unroll
                for (int j = 0; j < 8; j++) o[j] = 0;
            }
            *(short8*)(void*)&M[row][fb] = o;
        }
    }
    __syncthreads();

    // ---- GEMM tail: out = relu(M @ W') ; 8 waves cover 2x8 16x16 tiles ----
    int mrow = lane & 15;
    int quad = lane >> 4;
    int rt = wave >> 2;               // row tile 0..1
    int ctb = (wave & 3) * 2;         // col tile base 0,2,4,6
    floatx4 acc2[2];
    acc2[0] = {0.f, 0.f, 0.f, 0.f};
    acc2[1] = {0.f, 0.f, 0.f, 0.f};
#pragma unroll
    for (int k0 = 0; k0 < 128; k0 += 32) {
        short8 a = *(const short8*)(const void*)(&M[rt * 16 + mrow][k0 + quad * 8]);
#pragma unroll
        for (int t = 0; t < 2; t++) {
            short8 b = *(const short8*)(const void*)(&WT[(ctb + t) * 16 + mrow][k0 + quad * 8]);
            acc2[t] = __builtin_amdgcn_mfma_f32_16x16x32_bf16(a, b, acc2[t], 0, 0, 0);
        }
    }
#pragma unroll
    for (int t = 0; t < 2; t++) {
        int col = (ctb + t) * 16 + mrow;
#pragma unroll
        for (int i = 0; i < 4; i++) {
            int row = r0 + rt * 16 + quad * 4 + i;
            if (row < N_NODES) {
                float v = fmaxf(acc2[t][i], 0.f);
                size_t off = (size_t)row * DIM + col;
                if (outF) outF[off] = v;
                if (outB) outB[off] = f32_to_bf16(v);
            }
        }
    }
}

// ---------------- launch ----------------

extern "C" void kernel_launch(void* const* d_in, const int* in_sizes, int n_in,
                              void* d_out, int out_size, void* d_ws, size_t ws_size,
                              hipStream_t stream) {
    const float* x    = (const float*)d_in[0];
    const float* ew   = (const float*)d_in[1];
    const float* Wlin = (const float*)d_in[2];
    const float* blin = (const float*)d_in[3];
    const float* Wcv  = (const float*)d_in[4];
    const int* eidx = (const int*)d_in[5];
    const int* esrc = eidx;
    const int* edst = eidx + N_EDGES;
    float* out = (float*)d_out;

    char* ws = (char*)d_ws;
    unsigned short* x0B = (unsigned short*)(ws);             // 12.8 MB bf16 x0
    unsigned short* hA  = (unsigned short*)(ws + 12800000);  // 12.8 MB bf16 h ping
    unsigned short* hB2 = (unsigned short*)(ws + 25600000);  // 12.8 MB bf16 h pong
    int* cnt            = (int*)(ws + 38400000);             // N*4 degree
    int2* bucket        = (int2*)(ws + 38600064);            // N*PAD*8 = 48.0 MB
    unsigned short* WTg = (unsigned short*)(ws + 86600064);  // 288 KB
    int* histg          = (int*)(ws + 86894976);             // 391*197*4 = 308 KB
    // binbuf (6.4 MB) overlaps x0B: consumed by bin_scatter BEFORE gemm_x0
    int2* binbuf        = (int2*)ws;
    // total ~87.2 MB (under 89.8 MB known-good footprint)

    // prep: all 9 folded/transposed bf16 weight matrices (no counters left)
    prep<<<576, 256, 0, stream>>>(Wlin, Wcv, WTg);

    // sort-based bucket build (R17: no global atomics, write-combined)
    bin_sort<<<NBLKA, 256, 0, stream>>>(esrc, edst, ew, histg, binbuf);
    bin_scatter<<<NBIN * 2, 512, 0, stream>>>(histg, binbuf, cnt, bucket);

    // x0 gemm AFTER bin_scatter (x0B overlaps binbuf)
    gemm_x0<<<(N_NODES + 63) / 64, 256, 0, stream>>>(x, WTg, blin, x0B);

    const unsigned short* hin = x0B;
    for (int l = 0; l < 8; l++) {
        unsigned short* hout = (l == 7) ? nullptr : ((l & 1) ? hB2 : hA);
        layer_fused<<<1563, 512, 0, stream>>>(hin, x0B, cnt, bucket,
                                              WTg + (size_t)(1 + l) * 16384,
                                              (l == 7) ? out : nullptr, hout);
        hin = hout;
    }
}

// Round 6
// 453.489 us; speedup vs baseline: 1.3802x; 1.0030x over previous
//
#include <hip/hip_runtime.h>
#include <math.h>

#define N_NODES 50000
#define N_EDGES 800000
#define DIM 128
#define PAD 120                 // bucket capacity; realized max degree ~45

// R17 sort-based bucket build (both R4 failure modes addressed):
//  - no global atomics (R4: 1024-deep same-address chains @188ns = 192us)
//  - full-line single-block writes (R4: every 8B cross-XCD write = 64B wb)
#define EPB 2048                // edges per phase-A block
#define NBLKA 391               // ceil(800000/2048)
#define BIN_SHIFT 8
#define NBIN 196                // ceil(50000/256); bin = dst>>8
#define HISTW 197               // per-block stored scan: base[0..196]

typedef __attribute__((ext_vector_type(8))) short short8;
typedef __attribute__((ext_vector_type(4))) float floatx4;

// f32 -> bf16 bits, round-to-nearest-even (matches v_cvt / numpy)
__device__ __forceinline__ unsigned short f32_to_bf16(float f) {
    unsigned int u = __float_as_uint(f);
    u += 0x7fffu + ((u >> 16) & 1u);
    return (unsigned short)(u >> 16);
}
__device__ __forceinline__ float bf16_to_f32(unsigned short h) {
    return __uint_as_float((unsigned int)h << 16);
}

// R18: XOR-swizzled LDS addressing (replaces +8 padding -> LDS 43520->40960
// -> 4 blocks/CU instead of 3; layer gather is latency-bound at 42% occ).
// 16B-block index ^= row&7; all row offsets used are multiples of 16 so the
// writer/reader swizzles agree via mrow&7. Bank spread: start-bank =
// 4*((blk^(mrow&7))&7) -> exactly 8 lanes per 4-bank window (= structural
// minimum for wave64 b128, same as the padded layout it replaces).
__device__ __forceinline__ int swz(int row, int blk) {   // -> short index
    return row * 128 + (((blk ^ (row & 7)) & 15) << 3);
}

// ---------------- prep: build all 9 folded/transposed bf16 W ---------------
// Fold cg*W + cm*I ONCE (betas are compile-time constants of the layer idx).
// WTg layout: matrix m at m*16384, element [n][k] = W'[k][n] (transposed).
__global__ __launch_bounds__(256) void prep(const float* __restrict__ Wlin,
                                            const float* __restrict__ Wcv,
                                            unsigned short* __restrict__ WTg) {
    int i = blockIdx.x * 256 + threadIdx.x;   // grid 576*256 = 147456 = 9*16384
    int m = i >> 14;          // matrix 0..8
    int n = (i >> 7) & 127;   // output col (= row of WT)
    int k = i & 127;          // input dim
    float v;
    if (m == 0) {
        v = Wlin[k * 128 + n];
    } else {
        int l = m - 1;
        float beta = logf(0.5f / (float)(l + 1) + 1.0f);
        v = beta * Wcv[(size_t)l * 16384 + k * 128 + n]
            + ((n == k) ? (1.0f - beta) : 0.0f);
    }
    WTg[i] = f32_to_bf16(v);
}

// ---------------- phase A: block-local LDS counting sort -------------------
// Each block sorts its 2048 edges by dst-bin in LDS, then dumps the sorted
// buffer CONTIGUOUSLY (16KB, full-line coalesced, single-block-owned lines
// -> writeback == payload). Per-block bin starts (exclusive scan, 197 ints)
// go to histg. No global atomics anywhere; exact, no capacity clamp.
__global__ __launch_bounds__(256) void bin_sort(const int* __restrict__ src,
                                                const int* __restrict__ dst,
                                                const float* __restrict__ ew,
                                                int* __restrict__ histg,
                                                int2* __restrict__ binbuf) {
    __shared__ int hist[NBIN];
    __shared__ int base[NBIN + 1];
    __shared__ int cur[NBIN];
    __shared__ int2 sorted[EPB];          // 16 KB
    int tid = threadIdx.x;
    int e0 = blockIdx.x * EPB;
    if (tid < NBIN) hist[tid] = 0;
    __syncthreads();
    // pass 1: histogram of dst bins (LDS atomics, ~10-deep chains)
    for (int i = tid; i < EPB; i += 256) {
        int e = e0 + i;
        if (e < N_EDGES) atomicAdd(&hist[dst[e] >> BIN_SHIFT], 1);
    }
    __syncthreads();
    // exclusive scan base[0..196] (Hillis-Steele over 197 entries)
    if (tid < NBIN) base[tid + 1] = hist[tid];
    if (tid == 0) base[0] = 0;
    __syncthreads();
    for (int off = 1; off < NBIN + 1; off <<= 1) {
        int v = 0;
        if (tid >= off && tid <= NBIN) v = base[tid - off];
        __syncthreads();
        if (tid >= off && tid <= NBIN) base[tid] += v;
        __syncthreads();
    }
    if (tid < NBIN) cur[tid] = base[tid];
    __syncthreads();
    // pass 2: scatter into LDS sorted order (dst re-read is L2-hot)
    for (int i = tid; i < EPB; i += 256) {
        int e = e0 + i;
        if (e < N_EDGES) {
            int d = dst[e];
            int pos = atomicAdd(&cur[d >> BIN_SHIFT], 1);
            int2 p;
            p.x = (src[e] & 0xFFFF) | (d << 16);   // src<65536, d<65536
            p.y = __float_as_int(ew[e]);
            sorted[pos] = p;
        }
    }
    __syncthreads();
    int total = base[NBIN];
    // contiguous dump: full-line coalesced writes, block-exclusive lines
    for (int k = tid; k < total; k += 256)
        binbuf[(size_t)blockIdx.x * EPB + k] = sorted[k];
    // store the block's bin starts (exclusive scan incl. total at [196])
    if (tid <= NBIN) histg[blockIdx.x * HISTW + tid] = base[tid];
}

// ---------------- phase B: bin-local distribute to padded buckets ----------
// One block per (bin=256 nodes, half=128 nodes). Streams the bin's edges
// from all 391 block-segments (prefix-scan + binary search, all LDS), ranks
// per node via LDS atomics, writes buckets confined to a 16KB node range
// from a SINGLE block -> same-node writes land in one L2 residency window
// -> write-combined (R4 lesson: this is the only way to avoid E*64B wb).
__global__ __launch_bounds__(512) void bin_scatter(const int* __restrict__ histg,
                                                   const int2* __restrict__ binbuf,
                                                   int* __restrict__ cnt,
                                                   int2* __restrict__ bucket) {
    __shared__ int segstart[NBLKA];       // global slot of bin's chunk in seg s
    __shared__ int pref[NBLKA + 1];       // exclusive scan of chunk sizes
    __shared__ int c[128];
    int bin = blockIdx.x >> 1;
    int half = blockIdx.x & 1;
    int tid = threadIdx.x;
    if (tid < 128) c[tid] = 0;
    if (tid < NBLKA) {
        int bs = histg[tid * HISTW + bin];
        int be = histg[tid * HISTW + bin + 1];
        segstart[tid] = tid * EPB + bs;
        pref[tid + 1] = be - bs;
    }
    if (tid == 0) pref[0] = 0;
    __syncthreads();
    for (int off = 1; off < NBLKA + 1; off <<= 1) {
        int v = 0;
        if (tid >= off && tid <= NBLKA) v = pref[tid - off];
        __syncthreads();
        if (tid >= off && tid <= NBLKA) pref[tid] += v;
        __syncthreads();
    }
    int T = pref[NBLKA];
    for (int idx = tid; idx < T; idx += 512) {
        // find segment: largest s with pref[s] <= idx (LDS binary search)
        int lo = 0, hi = NBLKA - 1;
        while (lo < hi) {
            int mid = (lo + hi + 1) >> 1;
            if (pref[mid] <= idx) lo = mid; else hi = mid - 1;
        }
        int2 p = binbuf[(size_t)segstart[lo] + (idx - pref[lo])];
        int d = ((unsigned)p.x) >> 16;
        int dloc = d & ((1 << BIN_SHIFT) - 1);
        if ((dloc >> 7) == half) {
            int pos = atomicAdd(&c[dloc & 127], 1);
            if (pos < PAD) {               // realized max degree ~45, safe
                int2 q; q.x = p.x & 0xFFFF; q.y = p.y;
                bucket[(size_t)d * PAD + pos] = q;
            }
        }
    }
    __syncthreads();
    int node0 = (bin << BIN_SHIFT) + (half << 7);
    if (tid < 128 && node0 + tid < N_NODES)
        cnt[node0 + tid] = min(c[tid], PAD);
}

// ---------------- x0 = relu(x @ W_lin + b) -> bf16 rows --------------------
// B from prefolded bf16 WTg, staged through LDS (R14 proved in-loop global
// B-frag reads sit on the MFMA critical path; LDS ds_read_b128 ~12cy wins).
__global__ __launch_bounds__(256) void gemm_x0(const float* __restrict__ x,
                                               const unsigned short* __restrict__ WTg,
                                               const float* __restrict__ bias,
                                               unsigned short* __restrict__ x0B) {
    __shared__ unsigned short WT[128][136];   // +8 pad: 2-way max on b128 reads
    for (int idx = threadIdx.x; idx < 2048; idx += 256) {
        int n = idx >> 4, c = idx & 15;
        *(short8*)(void*)&WT[n][c * 8] =
            *(const short8*)(const void*)(WTg + n * 128 + c * 8);
    }
    __syncthreads();
    int wave = threadIdx.x >> 6;
    int lane = threadIdx.x & 63;
    int r0 = (blockIdx.x * 4 + wave) * 16;
    if (r0 >= N_NODES) return;                 // 16 | 50000, full tiles only
    int mrow = lane & 15;
    int quad = lane >> 4;
    floatx4 acc[8];
#pragma unroll
    for (int t = 0; t < 8; t++) acc[t] = {0.f, 0.f, 0.f, 0.f};
#pragma unroll
    for (int k0 = 0; k0 < 128; k0 += 32) {
        const float* arow = x + (size_t)(r0 + mrow) * DIM;
        floatx4 alo = *(const floatx4*)(const void*)(arow + k0 + quad * 8);
        floatx4 ahi = *(const floatx4*)(const void*)(arow + k0 + quad * 8 + 4);
        short8 a;
#pragma unroll
        for (int j = 0; j < 4; j++) a[j] = (short)f32_to_bf16(alo[j]);
#pragma unroll
        for (int j = 0; j < 4; j++) a[4 + j] = (short)f32_to_bf16(ahi[j]);
#pragma unroll
        for (int t = 0; t < 8; t++) {
            short8 b = *(const short8*)(const void*)(&WT[t * 16 + mrow][k0 + quad * 8]);
            acc[t] = __builtin_amdgcn_mfma_f32_16x16x32_bf16(a, b, acc[t], 0, 0, 0);
        }
    }
    // C/D layout: col = lane&15, row = quad*4 + i  [verified m89/m91]
#pragma unroll
    for (int t = 0; t < 8; t++) {
        int col = t * 16 + mrow;
        float bv = bias[col];
#pragma unroll
        for (int i = 0; i < 4; i++) {
            int row = r0 + quad * 4 + i;
            float v = fmaxf(acc[t][i] + bv, 0.f);
            x0B[(size_t)row * DIM + col] = f32_to_bf16(v);
        }
    }
}

// ---------------- fused SpMM + residual mix + GEMM (one dispatch/layer) ----
// R3-verified 46us-floor gather structure. R18: WT/M zero-pad + XOR swizzle
// -> LDS exactly 40960 B -> 4 blocks/CU (was 3 @ 43520). Gather phase is
// latency-bound (42% occ, VALU 38%, MFMA 1.2%, ~0.117 lines/cyc/CU) -> +33%
// resident waves = +33% outstanding line requests.
__global__ __launch_bounds__(512, 4) void layer_fused(
        const unsigned short* __restrict__ hB,
        const unsigned short* __restrict__ x0B,
        const int* __restrict__ cnt,
        const int2* __restrict__ bucket,
        const unsigned short* __restrict__ WTg,
        float* __restrict__ outF,
        unsigned short* __restrict__ outB) {
    __shared__ unsigned short WT[128 * 128];  // swizzled, no pad (32768 B)
    __shared__ unsigned short M[32 * 128];    // swizzled, no pad (8192 B)
    int tid = threadIdx.x;
    for (int idx = tid; idx < 2048; idx += 512) {
        int n = idx >> 4, c = idx & 15;
        *(short8*)(void*)&WT[swz(n, c)] =
            *(const short8*)(const void*)(WTg + n * 128 + c * 8);
    }
    int wave = tid >> 6;
    int lane = tid & 63;
    int eg = lane >> 4;               // edge group 0..3
    int fb = (lane & 15) * 8;         // feature octet
    int r0 = blockIdx.x * 32;

    for (int s = 0; s < 4; s++) {
        int row = (wave << 2) + s;    // 0..31, unique per (wave,s)
        int node = r0 + row;
        float acc[8] = {0.f, 0.f, 0.f, 0.f, 0.f, 0.f, 0.f, 0.f};
        if (node < N_NODES) {
            int end = min(cnt[node], PAD);
            if (end > 0) {
                const int2* ep = bucket + (size_t)node * PAD;
                int last = end - 1;
                for (int i = 0; i < end; i += 16) {
                    int i0 = i + eg, i1 = i0 + 4, i2 = i0 + 8, i3 = i0 + 12;
                    int2 e0 = ep[min(i0, last)];
                    int2 e1 = ep[min(i1, last)];
                    int2 e2 = ep[min(i2, last)];
                    int2 e3 = ep[min(i3, last)];
                    short8 r0v = *(const short8*)(const void*)(hB + (size_t)e0.x * DIM + fb);
                    short8 r1v = *(const short8*)(const void*)(hB + (size_t)e1.x * DIM + fb);
                    short8 r2v = *(const short8*)(const void*)(hB + (size_t)e2.x * DIM + fb);
                    short8 r3v = *(const short8*)(const void*)(hB + (size_t)e3.x * DIM + fb);
                    float w0 = (i0 < end) ? __int_as_float(e0.y) : 0.f;
                    float w1 = (i1 < end) ? __int_as_float(e1.y) : 0.f;
                    float w2 = (i2 < end) ? __int_as_float(e2.y) : 0.f;
                    float w3 = (i3 < end) ? __int_as_float(e3.y) : 0.f;
#pragma unroll
                    for (int j = 0; j < 8; j++) {
                        acc[j] = fmaf(w0, bf16_to_f32((unsigned short)r0v[j]), acc[j]);
                        acc[j] = fmaf(w1, bf16_to_f32((unsigned short)r1v[j]), acc[j]);
                        acc[j] = fmaf(w2, bf16_to_f32((unsigned short)r2v[j]), acc[j]);
                        acc[j] = fmaf(w3, bf16_to_f32((unsigned short)r3v[j]), acc[j]);
                    }
                }
            }
        }
        // reduce the 4 edge groups into lanes 0..15
#pragma unroll
        for (int j = 0; j < 8; j++) {
            acc[j] += __shfl_down(acc[j], 32);
            acc[j] += __shfl_down(acc[j], 16);
        }
        if (lane < 16) {
            short8 o;
            if (node < N_NODES) {
                short8 xv = *(const short8*)(const void*)(x0B + (size_t)node * DIM + fb);
#pragma unroll
                for (int j = 0; j < 8; j++)
                    o[j] = (short)f32_to_bf16(0.9f * acc[j]
                                              + 0.1f * bf16_to_f32((unsigned short)xv[j]));
            } else {
#pragma unroll
                for (int j = 0; j < 8; j++) o[j] = 0;
            }
            *(short8*)(void*)&M[swz(row, lane & 15)] = o;
        }
    }
    __syncthreads();

    // ---- GEMM tail: out = relu(M @ W') ; 8 waves cover 2x8 16x16 tiles ----
    int mrow = lane & 15;
    int quad = lane >> 4;
    int rt = wave >> 2;               // row tile 0..1
    int ctb = (wave & 3) * 2;         // col tile base 0,2,4,6
    floatx4 acc2[2];
    acc2[0] = {0.f, 0.f, 0.f, 0.f};
    acc2[1] = {0.f, 0.f, 0.f, 0.f};
#pragma unroll
    for (int k0 = 0; k0 < 128; k0 += 32) {
        short8 a = *(const short8*)(const void*)(&M[swz(rt * 16 + mrow, k0 / 8 + quad)]);
#pragma unroll
        for (int t = 0; t < 2; t++) {
            short8 b = *(const short8*)(const void*)(&WT[swz((ctb + t) * 16 + mrow, k0 / 8 + quad)]);
            acc2[t] = __builtin_amdgcn_mfma_f32_16x16x32_bf16(a, b, acc2[t], 0, 0, 0);
        }
    }
#pragma unroll
    for (int t = 0; t < 2; t++) {
        int col = (ctb + t) * 16 + mrow;
#pragma unroll
        for (int i = 0; i < 4; i++) {
            int row = r0 + rt * 16 + quad * 4 + i;
            if (row < N_NODES) {
                float v = fmaxf(acc2[t][i], 0.f);
                size_t off = (size_t)row * DIM + col;
                if (outF) outF[off] = v;
                if (outB) outB[off] = f32_to_bf16(v);
            }
        }
    }
}

// ---------------- launch ----------------

extern "C" void kernel_launch(void* const* d_in, const int* in_sizes, int n_in,
                              void* d_out, int out_size, void* d_ws, size_t ws_size,
                              hipStream_t stream) {
    const float* x    = (const float*)d_in[0];
    const float* ew   = (const float*)d_in[1];
    const float* Wlin = (const float*)d_in[2];
    const float* blin = (const float*)d_in[3];
    const float* Wcv  = (const float*)d_in[4];
    const int* eidx = (const int*)d_in[5];
    const int* esrc = eidx;
    const int* edst = eidx + N_EDGES;
    float* out = (float*)d_out;

    char* ws = (char*)d_ws;
    unsigned short* x0B = (unsigned short*)(ws);             // 12.8 MB bf16 x0
    unsigned short* hA  = (unsigned short*)(ws + 12800000);  // 12.8 MB bf16 h ping
    unsigned short* hB2 = (unsigned short*)(ws + 25600000);  // 12.8 MB bf16 h pong
    int* cnt            = (int*)(ws + 38400000);             // N*4 degree
    int2* bucket        = (int2*)(ws + 38600064);            // N*PAD*8 = 48.0 MB
    unsigned short* WTg = (unsigned short*)(ws + 86600064);  // 288 KB
    int* histg          = (int*)(ws + 86894976);             // 391*197*4 = 308 KB
    // binbuf (6.4 MB) overlaps x0B: consumed by bin_scatter BEFORE gemm_x0
    int2* binbuf        = (int2*)ws;
    // total ~87.2 MB (under 89.8 MB known-good footprint)

    // prep: all 9 folded/transposed bf16 weight matrices (no counters left)
    prep<<<576, 256, 0, stream>>>(Wlin, Wcv, WTg);

    // sort-based bucket build (R17: no global atomics, write-combined)
    bin_sort<<<NBLKA, 256, 0, stream>>>(esrc, edst, ew, histg, binbuf);
    bin_scatter<<<NBIN * 2, 512, 0, stream>>>(histg, binbuf, cnt, bucket);

    // x0 gemm AFTER bin_scatter (x0B overlaps binbuf)
    gemm_x0<<<(N_NODES + 63) / 64, 256, 0, stream>>>(x, WTg, blin, x0B);

    const unsigned short* hin = x0B;
    for (int l = 0; l < 8; l++) {
        unsigned short* hout = (l == 7) ? nullptr : ((l & 1) ? hB2 : hA);
        layer_fused<<<1563, 512, 0, stream>>>(hin, x0B, cnt, bucket,
                                              WTg + (size_t)(1 + l) * 16384,
                                              (l == 7) ? out : nullptr, hout);
        hin = hout;
    }
}

// Round 8
// 450.080 us; speedup vs baseline: 1.3907x; 1.0076x over previous
//
#include <hip/hip_runtime.h>
#include <math.h>

#define N_NODES 50000
#define N_EDGES 800000
#define DIM 128
#define PAD 120                 // bucket capacity; realized max degree ~45

// R19 bucket build: EPB 1024 (782 sort blocks, 2x fill), prep fat-merged,
// scan-free one-block-per-bin scatter. Constraints carried from R4/R17:
//  - no global atomics (same-address chains @188ns serialize)
//  - single-block line ownership for every global write (else 64B/8B wb amp)
//  - seg-chunks >= ~5 edges so binbuf reads stay line-efficient
#define EPB 1024                // edges per phase-A block
#define NBLKA 782               // ceil(800000/1024)
#define BIN_SHIFT 8
#define NBIN 196                // ceil(50000/256); bin = dst>>8
#define HISTW 197               // per-block stored scan: base[0..196]
#define PREP_BLOCKS 576         // 576*256 = 9*128*128 WTg elements

typedef __attribute__((ext_vector_type(8))) short short8;
typedef __attribute__((ext_vector_type(4))) float floatx4;

// f32 -> bf16 bits, round-to-nearest-even (matches v_cvt / numpy)
__device__ __forceinline__ unsigned short f32_to_bf16(float f) {
    unsigned int u = __float_as_uint(f);
    u += 0x7fffu + ((u >> 16) & 1u);
    return (unsigned short)(u >> 16);
}
__device__ __forceinline__ float bf16_to_f32(unsigned short h) {
    return __uint_as_float((unsigned int)h << 16);
}

// R18 XOR-swizzled LDS addressing (no pad, LDS 40960 B). Bank spread:
// start-bank = 4*((blk^(row&7))&7) -> 8 lanes per 4-bank window (structural
// minimum for wave64 b128, same as the padded layout it replaced).
__device__ __forceinline__ int swz(int row, int blk) {   // -> short index
    return row * 128 + (((blk ^ (row & 7)) & 15) << 3);
}

// ---------------- fat: block-local LDS counting sort || prep ---------------
// Blocks < NBLKA: sort 1024 edges by dst-bin in LDS, dump contiguously to
// binbuf (full-line coalesced, block-owned lines -> wb == payload), store
// per-block bin starts to histg. Blocks >= NBLKA: fold all 9 W' matrices
// (cg*W + cm*I, betas compile-time) into transposed bf16 WTg.
__global__ __launch_bounds__(256) void sortprep(const int* __restrict__ src,
                                                const int* __restrict__ dst,
                                                const float* __restrict__ ew,
                                                const float* __restrict__ Wlin,
                                                const float* __restrict__ Wcv,
                                                int* __restrict__ histg,
                                                int2* __restrict__ binbuf,
                                                unsigned short* __restrict__ WTg) {
    if (blockIdx.x >= NBLKA) {             // ---- prep tail (3us, hidden) ----
        int i = (blockIdx.x - NBLKA) * 256 + threadIdx.x;   // < 147456
        int m = i >> 14;          // matrix 0..8
        int n = (i >> 7) & 127;   // output col (= row of WT)
        int k = i & 127;          // input dim
        float v;
        if (m == 0) {
            v = Wlin[k * 128 + n];
        } else {
            int l = m - 1;
            float beta = logf(0.5f / (float)(l + 1) + 1.0f);
            v = beta * Wcv[(size_t)l * 16384 + k * 128 + n]
                + ((n == k) ? (1.0f - beta) : 0.0f);
        }
        WTg[i] = f32_to_bf16(v);
        return;
    }
    __shared__ int hist[NBIN];            // doubles as cursor after scan
    __shared__ int base[NBIN + 1];
    __shared__ int2 sorted[EPB];          // 8 KB
    int tid = threadIdx.x;
    int e0 = blockIdx.x * EPB;
    int n = min(EPB, N_EDGES - e0);
    if (tid < NBIN) hist[tid] = 0;
    __syncthreads();
    // pass 1: histogram of dst bins (LDS atomics, ~5-deep chains)
    for (int i = tid; i < n; i += 256) atomicAdd(&hist[dst[e0 + i] >> BIN_SHIFT], 1);
    __syncthreads();
    // exclusive scan base[0..196] (197 entries <= 256 threads: one Hillis)
    if (tid < NBIN) base[tid + 1] = hist[tid];
    if (tid == 0) base[0] = 0;
    __syncthreads();
    for (int off = 1; off < NBIN + 1; off <<= 1) {
        int v = 0;
        if (tid >= off && tid <= NBIN) v = base[tid - off];
        __syncthreads();
        if (tid >= off && tid <= NBIN) base[tid] += v;
        __syncthreads();
    }
    if (tid < NBIN) hist[tid] = base[tid];    // cur = base (reuse hist)
    __syncthreads();
    // pass 2: scatter into LDS sorted order (dst re-read is cache-hot)
    for (int i = tid; i < n; i += 256) {
        int e = e0 + i;
        int d = dst[e];
        int pos = atomicAdd(&hist[d >> BIN_SHIFT], 1);
        int2 p;
        p.x = (src[e] & 0xFFFF) | (d << 16);   // src<65536, d<65536
        p.y = __float_as_int(ew[e]);
        sorted[pos] = p;
    }
    __syncthreads();
    // contiguous dump: full-line coalesced writes, block-exclusive lines
    for (int k = tid; k < n; k += 256)
        binbuf[(size_t)blockIdx.x * EPB + k] = sorted[k];
    if (tid <= NBIN) histg[blockIdx.x * HISTW + tid] = base[tid];
}

// ---------------- phase B: scan-free bin-local distribute ------------------
// One 1024-thread block per bin (256 nodes). Thread t owns segment t: two
// histg reads (616KB table, L2-resident -> strided 4B READS are cheap; R4's
// amplification lesson applies to writes, not resident reads) give the
// chunk [bs,be) directly -- no per-block scan, no binary search. binbuf read
// exactly once (avg chunk 5.2 edges, contiguous). Bucket writes confined to
// the bin's 240KB window from a single block -> write-combined.
__global__ __launch_bounds__(1024) void bin_scatter(const int* __restrict__ histg,
                                                    const int2* __restrict__ binbuf,
                                                    int* __restrict__ cnt,
                                                    int2* __restrict__ bucket) {
    __shared__ int c[256];
    int bin = blockIdx.x;
    int tid = threadIdx.x;
    if (tid < 256) c[tid] = 0;
    __syncthreads();
    if (tid < NBLKA) {
        int bs = histg[tid * HISTW + bin];
        int be = histg[tid * HISTW + bin + 1];
        const int2* sp = binbuf + (size_t)tid * EPB;
        for (int k = bs; k < be; k++) {
            int2 p = sp[k];
            int d = ((unsigned)p.x) >> 16;
            int pos = atomicAdd(&c[d & 255], 1);
            if (pos < PAD) {               // realized max degree ~45, safe
                int2 q; q.x = p.x & 0xFFFF; q.y = p.y;
                bucket[(size_t)d * PAD + pos] = q;
            }
        }
    }
    __syncthreads();
    int node0 = bin << BIN_SHIFT;
    if (tid < 256 && node0 + tid < N_NODES)
        cnt[node0 + tid] = min(c[tid], PAD);
}

// ---------------- x0 = relu(x @ W_lin + b) -> bf16 rows --------------------
// B from prefolded bf16 WTg, staged through LDS (R14 proved in-loop global
// B-frag reads sit on the MFMA critical path; LDS ds_read_b128 ~12cy wins).
__global__ __launch_bounds__(256) void gemm_x0(const float* __restrict__ x,
                                               const unsigned short* __restrict__ WTg,
                                               const float* __restrict__ bias,
                                               unsigned short* __restrict__ x0B) {
    __shared__ unsigned short WT[128][136];   // +8 pad: 2-way max on b128 reads
    for (int idx = threadIdx.x; idx < 2048; idx += 256) {
        int n = idx >> 4, c = idx & 15;
        *(short8*)(void*)&WT[n][c * 8] =
            *(const short8*)(const void*)(WTg + n * 128 + c * 8);
    }
    __syncthreads();
    int wave = threadIdx.x >> 6;
    int lane = threadIdx.x & 63;
    int r0 = (blockIdx.x * 4 + wave) * 16;
    if (r0 >= N_NODES) return;                 // 16 | 50000, full tiles only
    int mrow = lane & 15;
    int quad = lane >> 4;
    floatx4 acc[8];
#pragma unroll
    for (int t = 0; t < 8; t++) acc[t] = {0.f, 0.f, 0.f, 0.f};
#pragma unroll
    for (int k0 = 0; k0 < 128; k0 += 32) {
        const float* arow = x + (size_t)(r0 + mrow) * DIM;
        floatx4 alo = *(const floatx4*)(const void*)(arow + k0 + quad * 8);
        floatx4 ahi = *(const floatx4*)(const void*)(arow + k0 + quad * 8 + 4);
        short8 a;
#pragma unroll
        for (int j = 0; j < 4; j++) a[j] = (short)f32_to_bf16(alo[j]);
#pragma unroll
        for (int j = 0; j < 4; j++) a[4 + j] = (short)f32_to_bf16(ahi[j]);
#pragma unroll
        for (int t = 0; t < 8; t++) {
            short8 b = *(const short8*)(const void*)(&WT[t * 16 + mrow][k0 + quad * 8]);
            acc[t] = __builtin_amdgcn_mfma_f32_16x16x32_bf16(a, b, acc[t], 0, 0, 0);
        }
    }
    // C/D layout: col = lane&15, row = quad*4 + i  [verified m89/m91]
#pragma unroll
    for (int t = 0; t < 8; t++) {
        int col = t * 16 + mrow;
        float bv = bias[col];
#pragma unroll
        for (int i = 0; i < 4; i++) {
            int row = r0 + quad * 4 + i;
            float v = fmaxf(acc[t][i] + bv, 0.f);
            x0B[(size_t)row * DIM + col] = f32_to_bf16(v);
        }
    }
}

// ---------------- fused SpMM + residual mix + GEMM (one dispatch/layer) ----
// AT FLOOR (R5/R6 evidence): 44.7us, occupancy-insensitive (42->44% occ at
// +1 block/CU headroom gave 0%), ~0.117 lines/cyc/CU random-line service,
// VALU 41% / MFMA 1.3% / 2.58 TB/s L2-miss BW. Do not touch.
__global__ __launch_bounds__(512, 4) void layer_fused(
        const unsigned short* __restrict__ hB,
        const unsigned short* __restrict__ x0B,
        const int* __restrict__ cnt,
        const int2* __restrict__ bucket,
        const unsigned short* __restrict__ WTg,
        float* __restrict__ outF,
        unsigned short* __restrict__ outB) {
    __shared__ unsigned short WT[128 * 128];  // swizzled, no pad (32768 B)
    __shared__ unsigned short M[32 * 128];    // swizzled, no pad (8192 B)
    int tid = threadIdx.x;
    for (int idx = tid; idx < 2048; idx += 512) {
        int n = idx >> 4, c = idx & 15;
        *(short8*)(void*)&WT[swz(n, c)] =
            *(const short8*)(const void*)(WTg + n * 128 + c * 8);
    }
    int wave = tid >> 6;
    int lane = tid & 63;
    int eg = lane >> 4;               // edge group 0..3
    int fb = (lane & 15) * 8;         // feature octet
    int r0 = blockIdx.x * 32;

    for (int s = 0; s < 4; s++) {
        int row = (wave << 2) + s;    // 0..31, unique per (wave,s)
        int node = r0 + row;
        float acc[8] = {0.f, 0.f, 0.f, 0.f, 0.f, 0.f, 0.f, 0.f};
        if (node < N_NODES) {
            int end = min(cnt[node], PAD);
            if (end > 0) {
                const int2* ep = bucket + (size_t)node * PAD;
                int last = end - 1;
                for (int i = 0; i < end; i += 16) {
                    int i0 = i + eg, i1 = i0 + 4, i2 = i0 + 8, i3 = i0 + 12;
                    int2 e0 = ep[min(i0, last)];
                    int2 e1 = ep[min(i1, last)];
                    int2 e2 = ep[min(i2, last)];
                    int2 e3 = ep[min(i3, last)];
                    short8 r0v = *(const short8*)(const void*)(hB + (size_t)e0.x * DIM + fb);
                    short8 r1v = *(const short8*)(const void*)(hB + (size_t)e1.x * DIM + fb);
                    short8 r2v = *(const short8*)(const void*)(hB + (size_t)e2.x * DIM + fb);
                    short8 r3v = *(const short8*)(const void*)(hB + (size_t)e3.x * DIM + fb);
                    float w0 = (i0 < end) ? __int_as_float(e0.y) : 0.f;
                    float w1 = (i1 < end) ? __int_as_float(e1.y) : 0.f;
                    float w2 = (i2 < end) ? __int_as_float(e2.y) : 0.f;
                    float w3 = (i3 < end) ? __int_as_float(e3.y) : 0.f;
#pragma unroll
                    for (int j = 0; j < 8; j++) {
                        acc[j] = fmaf(w0, bf16_to_f32((unsigned short)r0v[j]), acc[j]);
                        acc[j] = fmaf(w1, bf16_to_f32((unsigned short)r1v[j]), acc[j]);
                        acc[j] = fmaf(w2, bf16_to_f32((unsigned short)r2v[j]), acc[j]);
                        acc[j] = fmaf(w3, bf16_to_f32((unsigned short)r3v[j]), acc[j]);
                    }
                }
            }
        }
        // reduce the 4 edge groups into lanes 0..15
#pragma unroll
        for (int j = 0; j < 8; j++) {
            acc[j] += __shfl_down(acc[j], 32);
            acc[j] += __shfl_down(acc[j], 16);
        }
        if (lane < 16) {
            short8 o;
            if (node < N_NODES) {
                short8 xv = *(const short8*)(const void*)(x0B + (size_t)node * DIM + fb);
#pragma unroll
                for (int j = 0; j < 8; j++)
                    o[j] = (short)f32_to_bf16(0.9f * acc[j]
                                              + 0.1f * bf16_to_f32((unsigned short)xv[j]));
            } else {
#pragma unroll
                for (int j = 0; j < 8; j++) o[j] = 0;
            }
            *(short8*)(void*)&M[swz(row, lane & 15)] = o;
        }
    }
    __syncthreads();

    // ---- GEMM tail: out = relu(M @ W') ; 8 waves cover 2x8 16x16 tiles ----
    int mrow = lane & 15;
    int quad = lane >> 4;
    int rt = wave >> 2;               // row tile 0..1
    int ctb = (wave & 3) * 2;         // col tile base 0,2,4,6
    floatx4 acc2[2];
    acc2[0] = {0.f, 0.f, 0.f, 0.f};
    acc2[1] = {0.f, 0.f, 0.f, 0.f};
#pragma unroll
    for (int k0 = 0; k0 < 128; k0 += 32) {
        short8 a = *(const short8*)(const void*)(&M[swz(rt * 16 + mrow, k0 / 8 + quad)]);
#pragma unroll
        for (int t = 0; t < 2; t++) {
            short8 b = *(const short8*)(const void*)(&WT[swz((ctb + t) * 16 + mrow, k0 / 8 + quad)]);
            acc2[t] = __builtin_amdgcn_mfma_f32_16x16x32_bf16(a, b, acc2[t], 0, 0, 0);
        }
    }
#pragma unroll
    for (int t = 0; t < 2; t++) {
        int col = (ctb + t) * 16 + mrow;
#pragma unroll
        for (int i = 0; i < 4; i++) {
            int row = r0 + rt * 16 + quad * 4 + i;
            if (row < N_NODES) {
                float v = fmaxf(acc2[t][i], 0.f);
                size_t off = (size_t)row * DIM + col;
                if (outF) outF[off] = v;
                if (outB) outB[off] = f32_to_bf16(v);
            }
        }
    }
}

// ---------------- launch ----------------

extern "C" void kernel_launch(void* const* d_in, const int* in_sizes, int n_in,
                              void* d_out, int out_size, void* d_ws, size_t ws_size,
                              hipStream_t stream) {
    const float* x    = (const float*)d_in[0];
    const float* ew   = (const float*)d_in[1];
    const float* Wlin = (const float*)d_in[2];
    const float* blin = (const float*)d_in[3];
    const float* Wcv  = (const float*)d_in[4];
    const int* eidx = (const int*)d_in[5];
    const int* esrc = eidx;
    const int* edst = eidx + N_EDGES;
    float* out = (float*)d_out;

    char* ws = (char*)d_ws;
    unsigned short* x0B = (unsigned short*)(ws);             // 12.8 MB bf16 x0
    unsigned short* hA  = (unsigned short*)(ws + 12800000);  // 12.8 MB bf16 h ping
    unsigned short* hB2 = (unsigned short*)(ws + 25600000);  // 12.8 MB bf16 h pong
    int* cnt            = (int*)(ws + 38400000);             // N*4 degree
    int2* bucket        = (int2*)(ws + 38600064);            // N*PAD*8 = 48.0 MB
    unsigned short* WTg = (unsigned short*)(ws + 86600064);  // 288 KB
    int* histg          = (int*)(ws + 86894976);             // 782*197*4 = 616 KB
    // binbuf (6.4 MB) overlaps x0B: consumed by bin_scatter BEFORE gemm_x0
    int2* binbuf        = (int2*)ws;
    // total ~87.5 MB (under 89.8 MB known-good footprint)

    // sort (782 blocks) || prep (576 blocks): one dispatch
    sortprep<<<NBLKA + PREP_BLOCKS, 256, 0, stream>>>(esrc, edst, ew, Wlin, Wcv,
                                                      histg, binbuf, WTg);

    // scan-free bin-local distribute
    bin_scatter<<<NBIN, 1024, 0, stream>>>(histg, binbuf, cnt, bucket);

    // x0 gemm AFTER bin_scatter (x0B overlaps binbuf)
    gemm_x0<<<(N_NODES + 63) / 64, 256, 0, stream>>>(x, WTg, blin, x0B);

    const unsigned short* hin = x0B;
    for (int l = 0; l < 8; l++) {
        unsigned short* hout = (l == 7) ? nullptr : ((l & 1) ? hB2 : hA);
        layer_fused<<<1563, 512, 0, stream>>>(hin, x0B, cnt, bucket,
                                              WTg + (size_t)(1 + l) * 16384,
                                              (l == 7) ? out : nullptr, hout);
        hin = hout;
    }
}

// Round 9
// 449.910 us; speedup vs baseline: 1.3912x; 1.0004x over previous
//
#include <hip/hip_runtime.h>
#include <math.h>

#define N_NODES 50000
#define N_EDGES 800000
#define DIM 128
#define PAD 120                 // bucket capacity; realized max degree ~45

// R19 bucket build constraints (carried from R4/R17):
//  - no global atomics (same-address chains @188ns serialize)
//  - single-block line ownership for every global write (else 64B/8B wb amp)
//  - seg-chunks >= ~5 edges so binbuf reads stay line-efficient
#define EPB 1024                // edges per phase-A block
#define NBLKA 782               // ceil(800000/1024)
#define BIN_SHIFT 8
#define NBIN 196                // ceil(50000/256); bin = dst>>8
#define HISTW 197               // per-block stored scan: base[0..196]
#define PREP_BLOCKS 576         // 576*256 = 9*128*128 WTg elements
#define GEMM_BLOCKS 391         // 391 blocks * 8 waves * 16 rows >= 50000

typedef __attribute__((ext_vector_type(8))) short short8;
typedef __attribute__((ext_vector_type(4))) float floatx4;

// f32 -> bf16 bits, round-to-nearest-even (matches v_cvt / numpy)
__device__ __forceinline__ unsigned short f32_to_bf16(float f) {
    unsigned int u = __float_as_uint(f);
    u += 0x7fffu + ((u >> 16) & 1u);
    return (unsigned short)(u >> 16);
}
__device__ __forceinline__ float bf16_to_f32(unsigned short h) {
    return __uint_as_float((unsigned int)h << 16);
}

// R18 XOR-swizzled LDS addressing (no pad, LDS 40960 B). Bank spread:
// start-bank = 4*((blk^(row&7))&7) -> 8 lanes per 4-bank window (structural
// minimum for wave64 b128, same as the padded layout it replaced).
__device__ __forceinline__ int swz(int row, int blk) {   // -> short index
    return row * 128 + (((blk ^ (row & 7)) & 15) << 3);
}

// ---------------- fat: block-local LDS counting sort || prep ---------------
// Blocks < NBLKA: sort 1024 edges by dst-bin in LDS, dump contiguously to
// binbuf (full-line coalesced, block-owned lines -> wb == payload), store
// per-block bin starts to histg. Blocks >= NBLKA: fold all 9 W' matrices
// (cg*W + cm*I, betas compile-time) into transposed bf16 WTg.
__global__ __launch_bounds__(256) void sortprep(const int* __restrict__ src,
                                                const int* __restrict__ dst,
                                                const float* __restrict__ ew,
                                                const float* __restrict__ Wlin,
                                                const float* __restrict__ Wcv,
                                                int* __restrict__ histg,
                                                int2* __restrict__ binbuf,
                                                unsigned short* __restrict__ WTg) {
    if (blockIdx.x >= NBLKA) {             // ---- prep tail (3us, hidden) ----
        int i = (blockIdx.x - NBLKA) * 256 + threadIdx.x;   // < 147456
        int m = i >> 14;          // matrix 0..8
        int n = (i >> 7) & 127;   // output col (= row of WT)
        int k = i & 127;          // input dim
        float v;
        if (m == 0) {
            v = Wlin[k * 128 + n];
        } else {
            int l = m - 1;
            float beta = logf(0.5f / (float)(l + 1) + 1.0f);
            v = beta * Wcv[(size_t)l * 16384 + k * 128 + n]
                + ((n == k) ? (1.0f - beta) : 0.0f);
        }
        WTg[i] = f32_to_bf16(v);
        return;
    }
    __shared__ int hist[NBIN];            // doubles as cursor after scan
    __shared__ int base[NBIN + 1];
    __shared__ int2 sorted[EPB];          // 8 KB
    int tid = threadIdx.x;
    int e0 = blockIdx.x * EPB;
    int n = min(EPB, N_EDGES - e0);
    if (tid < NBIN) hist[tid] = 0;
    __syncthreads();
    // pass 1: histogram of dst bins (LDS atomics, ~5-deep chains)
    for (int i = tid; i < n; i += 256) atomicAdd(&hist[dst[e0 + i] >> BIN_SHIFT], 1);
    __syncthreads();
    // exclusive scan base[0..196] (197 entries <= 256 threads: one Hillis)
    if (tid < NBIN) base[tid + 1] = hist[tid];
    if (tid == 0) base[0] = 0;
    __syncthreads();
    for (int off = 1; off < NBIN + 1; off <<= 1) {
        int v = 0;
        if (tid >= off && tid <= NBIN) v = base[tid - off];
        __syncthreads();
        if (tid >= off && tid <= NBIN) base[tid] += v;
        __syncthreads();
    }
    if (tid < NBIN) hist[tid] = base[tid];    // cur = base (reuse hist)
    __syncthreads();
    // pass 2: scatter into LDS sorted order (dst re-read is cache-hot)
    for (int i = tid; i < n; i += 256) {
        int e = e0 + i;
        int d = dst[e];
        int pos = atomicAdd(&hist[d >> BIN_SHIFT], 1);
        int2 p;
        p.x = (src[e] & 0xFFFF) | (d << 16);   // src<65536, d<65536
        p.y = __float_as_int(ew[e]);
        sorted[pos] = p;
    }
    __syncthreads();
    // contiguous dump: full-line coalesced writes, block-exclusive lines
    for (int k = tid; k < n; k += 256)
        binbuf[(size_t)blockIdx.x * EPB + k] = sorted[k];
    if (tid <= NBIN) histg[blockIdx.x * HISTW + tid] = base[tid];
}

// ---------------- fatB: bin-local distribute || x0 GEMM --------------------
// R20: bin_scatter (196 blocks, 0.77/CU, latency-bound) and gemm_x0 are
// independent -> one 587-block dispatch. No global atomics / no random-line
// writebacks on the scatter side, so the R2 fusion-interference mode (3.2M
// random atomic RMWs) does not apply. binbuf lives in hB2 (dead until layer
// 1) so the gemm's x0B writes cannot race the scatter's binbuf reads.
__global__ __launch_bounds__(512) void fatB(const int* __restrict__ histg,
                                            const int2* __restrict__ binbuf,
                                            int* __restrict__ cnt,
                                            int2* __restrict__ bucket,
                                            const float* __restrict__ x,
                                            const unsigned short* __restrict__ WTg,
                                            const float* __restrict__ bias,
                                            unsigned short* __restrict__ x0B) {
    __shared__ unsigned short WT[128][136];   // gemm blocks only
    __shared__ int c[256];                    // scatter blocks only
    int tid = threadIdx.x;
    if (blockIdx.x < NBIN) {
        // ---- scatter: one block per bin (256 nodes); thread t owns segs
        // t, t+512. Two histg reads per seg (L2-resident strided 4B reads);
        // binbuf read once, contiguous per chunk. Bucket writes confined to
        // the bin's 240KB window from one block -> write-combined.
        int bin = blockIdx.x;
        if (tid < 256) c[tid] = 0;
        __syncthreads();
        for (int t = tid; t < NBLKA; t += 512) {
            int bs = histg[t * HISTW + bin];
            int be = histg[t * HISTW + bin + 1];
            const int2* sp = binbuf + (size_t)t * EPB;
            for (int k = bs; k < be; k++) {
                int2 p = sp[k];
                int d = ((unsigned)p.x) >> 16;
                int pos = atomicAdd(&c[d & 255], 1);
                if (pos < PAD) {               // realized max degree ~45, safe
                    int2 q; q.x = p.x & 0xFFFF; q.y = p.y;
                    bucket[(size_t)d * PAD + pos] = q;
                }
            }
        }
        __syncthreads();
        int node0 = bin << BIN_SHIFT;
        if (tid < 256 && node0 + tid < N_NODES)
            cnt[node0 + tid] = min(c[tid], PAD);
        return;
    }
    // ---- x0 = relu(x @ W_lin + b) -> bf16 rows; 8 waves x 16-row tiles ----
    for (int idx = tid; idx < 2048; idx += 512) {
        int n = idx >> 4, cc = idx & 15;
        *(short8*)(void*)&WT[n][cc * 8] =
            *(const short8*)(const void*)(WTg + n * 128 + cc * 8);
    }
    __syncthreads();
    int wave = tid >> 6;
    int lane = tid & 63;
    int r0 = ((blockIdx.x - NBIN) * 8 + wave) * 16;
    if (r0 >= N_NODES) return;                 // last 3 waves of last block
    int mrow = lane & 15;
    int quad = lane >> 4;
    floatx4 acc[8];
#pragma unroll
    for (int t = 0; t < 8; t++) acc[t] = {0.f, 0.f, 0.f, 0.f};
#pragma unroll
    for (int k0 = 0; k0 < 128; k0 += 32) {
        const float* arow = x + (size_t)(r0 + mrow) * DIM;
        floatx4 alo = *(const floatx4*)(const void*)(arow + k0 + quad * 8);
        floatx4 ahi = *(const floatx4*)(const void*)(arow + k0 + quad * 8 + 4);
        short8 a;
#pragma unroll
        for (int j = 0; j < 4; j++) a[j] = (short)f32_to_bf16(alo[j]);
#pragma unroll
        for (int j = 0; j < 4; j++) a[4 + j] = (short)f32_to_bf16(ahi[j]);
#pragma unroll
        for (int t = 0; t < 8; t++) {
            short8 b = *(const short8*)(const void*)(&WT[t * 16 + mrow][k0 + quad * 8]);
            acc[t] = __builtin_amdgcn_mfma_f32_16x16x32_bf16(a, b, acc[t], 0, 0, 0);
        }
    }
    // C/D layout: col = lane&15, row = quad*4 + i  [verified m89/m91]
#pragma unroll
    for (int t = 0; t < 8; t++) {
        int col = t * 16 + mrow;
        float bv = bias[col];
#pragma unroll
        for (int i = 0; i < 4; i++) {
            int row = r0 + quad * 4 + i;
            float v = fmaxf(acc[t][i] + bv, 0.f);
            x0B[(size_t)row * DIM + col] = f32_to_bf16(v);
        }
    }
}

// ---------------- fused SpMM + residual mix + GEMM (one dispatch/layer) ----
// AT FLOOR (R5/R6/R8 evidence): 44.7us, occupancy-insensitive, ~0.117
// lines/cyc/CU random-line service, 2.59 TB/s L2-miss BW, FETCH 88MB vs
// 12.8MB state (inherent random re-fetch: working set > per-XCD L2).
__global__ __launch_bounds__(512, 4) void layer_fused(
        const unsigned short* __restrict__ hB,
        const unsigned short* __restrict__ x0B,
        const int* __restrict__ cnt,
        const int2* __restrict__ bucket,
        const unsigned short* __restrict__ WTg,
        float* __restrict__ outF,
        unsigned short* __restrict__ outB) {
    __shared__ unsigned short WT[128 * 128];  // swizzled, no pad (32768 B)
    __shared__ unsigned short M[32 * 128];    // swizzled, no pad (8192 B)
    int tid = threadIdx.x;
    for (int idx = tid; idx < 2048; idx += 512) {
        int n = idx >> 4, c = idx & 15;
        *(short8*)(void*)&WT[swz(n, c)] =
            *(const short8*)(const void*)(WTg + n * 128 + c * 8);
    }
    int wave = tid >> 6;
    int lane = tid & 63;
    int eg = lane >> 4;               // edge group 0..3
    int fb = (lane & 15) * 8;         // feature octet
    int r0 = blockIdx.x * 32;

    for (int s = 0; s < 4; s++) {
        int row = (wave << 2) + s;    // 0..31, unique per (wave,s)
        int node = r0 + row;
        float acc[8] = {0.f, 0.f, 0.f, 0.f, 0.f, 0.f, 0.f, 0.f};
        if (node < N_NODES) {
            int end = min(cnt[node], PAD);
            if (end > 0) {
                const int2* ep = bucket + (size_t)node * PAD;
                int last = end - 1;
                for (int i = 0; i < end; i += 16) {
                    int i0 = i + eg, i1 = i0 + 4, i2 = i0 + 8, i3 = i0 + 12;
                    int2 e0 = ep[min(i0, last)];
                    int2 e1 = ep[min(i1, last)];
                    int2 e2 = ep[min(i2, last)];
                    int2 e3 = ep[min(i3, last)];
                    short8 r0v = *(const short8*)(const void*)(hB + (size_t)e0.x * DIM + fb);
                    short8 r1v = *(const short8*)(const void*)(hB + (size_t)e1.x * DIM + fb);
                    short8 r2v = *(const short8*)(const void*)(hB + (size_t)e2.x * DIM + fb);
                    short8 r3v = *(const short8*)(const void*)(hB + (size_t)e3.x * DIM + fb);
                    float w0 = (i0 < end) ? __int_as_float(e0.y) : 0.f;
                    float w1 = (i1 < end) ? __int_as_float(e1.y) : 0.f;
                    float w2 = (i2 < end) ? __int_as_float(e2.y) : 0.f;
                    float w3 = (i3 < end) ? __int_as_float(e3.y) : 0.f;
#pragma unroll
                    for (int j = 0; j < 8; j++) {
                        acc[j] = fmaf(w0, bf16_to_f32((unsigned short)r0v[j]), acc[j]);
                        acc[j] = fmaf(w1, bf16_to_f32((unsigned short)r1v[j]), acc[j]);
                        acc[j] = fmaf(w2, bf16_to_f32((unsigned short)r2v[j]), acc[j]);
                        acc[j] = fmaf(w3, bf16_to_f32((unsigned short)r3v[j]), acc[j]);
                    }
                }
            }
        }
        // reduce the 4 edge groups into lanes 0..15
#pragma unroll
        for (int j = 0; j < 8; j++) {
            acc[j] += __shfl_down(acc[j], 32);
            acc[j] += __shfl_down(acc[j], 16);
        }
        if (lane < 16) {
            short8 o;
            if (node < N_NODES) {
                short8 xv = *(const short8*)(const void*)(x0B + (size_t)node * DIM + fb);
#pragma unroll
                for (int j = 0; j < 8; j++)
                    o[j] = (short)f32_to_bf16(0.9f * acc[j]
                                              + 0.1f * bf16_to_f32((unsigned short)xv[j]));
            } else {
#pragma unroll
                for (int j = 0; j < 8; j++) o[j] = 0;
            }
            *(short8*)(void*)&M[swz(row, lane & 15)] = o;
        }
    }
    __syncthreads();

    // ---- GEMM tail: out = relu(M @ W') ; 8 waves cover 2x8 16x16 tiles ----
    int mrow = lane & 15;
    int quad = lane >> 4;
    int rt = wave >> 2;               // row tile 0..1
    int ctb = (wave & 3) * 2;         // col tile base 0,2,4,6
    floatx4 acc2[2];
    acc2[0] = {0.f, 0.f, 0.f, 0.f};
    acc2[1] = {0.f, 0.f, 0.f, 0.f};
#pragma unroll
    for (int k0 = 0; k0 < 128; k0 += 32) {
        short8 a = *(const short8*)(const void*)(&M[swz(rt * 16 + mrow, k0 / 8 + quad)]);
#pragma unroll
        for (int t = 0; t < 2; t++) {
            short8 b = *(const short8*)(const void*)(&WT[swz((ctb + t) * 16 + mrow, k0 / 8 + quad)]);
            acc2[t] = __builtin_amdgcn_mfma_f32_16x16x32_bf16(a, b, acc2[t], 0, 0, 0);
        }
    }
#pragma unroll
    for (int t = 0; t < 2; t++) {
        int col = (ctb + t) * 16 + mrow;
#pragma unroll
        for (int i = 0; i < 4; i++) {
            int row = r0 + rt * 16 + quad * 4 + i;
            if (row < N_NODES) {
                float v = fmaxf(acc2[t][i], 0.f);
                size_t off = (size_t)row * DIM + col;
                if (outF) outF[off] = v;
                if (outB) outB[off] = f32_to_bf16(v);
            }
        }
    }
}

// ---------------- launch ----------------

extern "C" void kernel_launch(void* const* d_in, const int* in_sizes, int n_in,
                              void* d_out, int out_size, void* d_ws, size_t ws_size,
                              hipStream_t stream) {
    const float* x    = (const float*)d_in[0];
    const float* ew   = (const float*)d_in[1];
    const float* Wlin = (const float*)d_in[2];
    const float* blin = (const float*)d_in[3];
    const float* Wcv  = (const float*)d_in[4];
    const int* eidx = (const int*)d_in[5];
    const int* esrc = eidx;
    const int* edst = eidx + N_EDGES;
    float* out = (float*)d_out;

    char* ws = (char*)d_ws;
    unsigned short* x0B = (unsigned short*)(ws);             // 12.8 MB bf16 x0
    unsigned short* hA  = (unsigned short*)(ws + 12800000);  // 12.8 MB bf16 h ping
    unsigned short* hB2 = (unsigned short*)(ws + 25600000);  // 12.8 MB bf16 h pong
    int* cnt            = (int*)(ws + 38400000);             // N*4 degree
    int2* bucket        = (int2*)(ws + 38600064);            // N*PAD*8 = 48.0 MB
    unsigned short* WTg = (unsigned short*)(ws + 86600064);  // 288 KB
    int* histg          = (int*)(ws + 86894976);             // 782*197*4 = 616 KB
    // binbuf (6.4 MB) overlaps hB2: dead after fatB, first rewritten by
    // layer 1 -> fatB's gemm half can write x0B with no race.
    int2* binbuf        = (int2*)hB2;
    // total ~87.5 MB (under 89.8 MB known-good footprint)

    // sort (782 blocks) || prep (576 blocks): one dispatch
    sortprep<<<NBLKA + PREP_BLOCKS, 256, 0, stream>>>(esrc, edst, ew, Wlin, Wcv,
                                                      histg, binbuf, WTg);

    // distribute (196 blocks) || x0 gemm (391 blocks): one dispatch
    fatB<<<NBIN + GEMM_BLOCKS, 512, 0, stream>>>(histg, binbuf, cnt, bucket,
                                                 x, WTg, blin, x0B);

    const unsigned short* hin = x0B;
    for (int l = 0; l < 8; l++) {
        unsigned short* hout = (l == 7) ? nullptr : ((l & 1) ? hB2 : hA);
        layer_fused<<<1563, 512, 0, stream>>>(hin, x0B, cnt, bucket,
                                              WTg + (size_t)(1 + l) * 16384,
                                              (l == 7) ? out : nullptr, hout);
        hin = hout;
    }
}